// Round 17
// baseline (372.014 us; speedup 1.0000x reference)
//
#include <hip/hip_runtime.h>
#include <stdint.h>

typedef unsigned short u16;
typedef short s8v __attribute__((ext_vector_type(8)));
typedef float f32x4 __attribute__((ext_vector_type(4)));

#define B_SZ 4
#define T_SEQ 2048
#define E_DIM 1024
#define H_NUM 16
#define HS 64
#define FF_DIM 4096
#define M_ROWS 8192  // B*T
// Q pre-scale: E^-0.5 * log2(e) -> QK^T scores arrive in log2 domain
#define QSCALE 0.0450842200f

__device__ __forceinline__ u16 f2bf(float f) {
    unsigned int u = __builtin_bit_cast(unsigned int, f);
    u += 0x7fffu + ((u >> 16) & 1u);
    return (u16)(u >> 16);
}

__device__ __forceinline__ float bf2f(u16 u) {
    unsigned int v = ((unsigned int)u) << 16;
    return __builtin_bit_cast(float, v);
}

__device__ __forceinline__ void async_copy16(const void* g, void* l) {
    __builtin_amdgcn_global_load_lds(
        (const __attribute__((address_space(1))) unsigned int*)g,
        (__attribute__((address_space(3))) unsigned int*)l, 16, 0, 0);
}

// ------- batched transpose + cast for the four 1024x1024 weights (Wq,Wk,Wv,Wp) -----
__global__ __launch_bounds__(256)
void transpose_cast4(const float* __restrict__ s0, const float* __restrict__ s1,
                     const float* __restrict__ s2, const float* __restrict__ s3,
                     u16* __restrict__ dqkv, u16* __restrict__ dp) {
    __shared__ float tile[32][33];
    const int zz = blockIdx.z;
    const float* src = (zz == 0) ? s0 : (zz == 1) ? s1 : (zz == 2) ? s2 : s3;
    u16* dst = (zz < 3) ? dqkv + (size_t)zz * 1048576 : dp;
    int n0 = blockIdx.x * 32, k0 = blockIdx.y * 32;
    int tx = threadIdx.x, ty = threadIdx.y;
#pragma unroll
    for (int i = 0; i < 4; i++)
        tile[ty + i * 8][tx] = src[(size_t)(k0 + ty + i * 8) * 1024 + n0 + tx];
    __syncthreads();
#pragma unroll
    for (int i = 0; i < 4; i++)
        dst[(size_t)(n0 + ty + i * 8) * 1024 + k0 + tx] = f2bf(tile[tx][ty + i * 8]);
}

// ------- merged transpose + cast for W1 [1024][4096] and W2 [4096][1024] -----------
__global__ __launch_bounds__(256)
void transpose_cast_w12(const float* __restrict__ W1, const float* __restrict__ W2,
                        u16* __restrict__ d1, u16* __restrict__ d2) {
    __shared__ float tile[32][33];
    const int zz = blockIdx.z;
    const float* src;
    u16* dst;
    int n0, k0, N, K;
    if (zz == 0) {  // W1: src [1024][4096] -> dst [4096][1024]
        src = W1; dst = d1; N = 4096; K = 1024;
        n0 = blockIdx.x * 32; k0 = blockIdx.y * 32;
    } else {        // W2: src [4096][1024] -> dst [1024][4096]
        src = W2; dst = d2; N = 1024; K = 4096;
        int idx = blockIdx.y * 128 + blockIdx.x;   // 0..4095
        n0 = (idx & 31) * 32; k0 = (idx >> 5) * 32;
    }
    int tx = threadIdx.x, ty = threadIdx.y;
#pragma unroll
    for (int i = 0; i < 4; i++)
        tile[ty + i * 8][tx] = src[(size_t)(k0 + ty + i * 8) * N + n0 + tx];
    __syncthreads();
#pragma unroll
    for (int i = 0; i < 4; i++)
        dst[(size_t)(n0 + ty + i * 8) * K + k0 + tx] = f2bf(tile[tx][ty + i * 8]);
}

// ---------------- LayerNorm (E=1024) + bf16 cast, f32 input ------------------------
__global__ __launch_bounds__(256)
void ln_kernel(const float* __restrict__ x, const float* __restrict__ g,
               const float* __restrict__ b, u16* __restrict__ out) {
    int row = blockIdx.x;
    int tid = threadIdx.x;
    float4 v = ((const float4*)(x + (size_t)row * E_DIM))[tid];
    float s = v.x + v.y + v.z + v.w;
    float sq = v.x * v.x + v.y * v.y + v.z * v.z + v.w * v.w;
#pragma unroll
    for (int off = 32; off; off >>= 1) {
        s += __shfl_xor(s, off);
        sq += __shfl_xor(sq, off);
    }
    __shared__ float sh[8];
    int w = tid >> 6, lane = tid & 63;
    if (lane == 0) { sh[w] = s; sh[4 + w] = sq; }
    __syncthreads();
    s = sh[0] + sh[1] + sh[2] + sh[3];
    sq = sh[4] + sh[5] + sh[6] + sh[7];
    float mu = s * (1.f / E_DIM);
    float var = sq * (1.f / E_DIM) - mu * mu;
    float rs = rsqrtf(var + 1e-5f);
    float4 gv = ((const float4*)g)[tid];
    float4 bv = ((const float4*)b)[tid];
    ushort4 o;
    o.x = f2bf((v.x - mu) * rs * gv.x + bv.x);
    o.y = f2bf((v.y - mu) * rs * gv.y + bv.y);
    o.z = f2bf((v.z - mu) * rs * gv.z + bv.z);
    o.w = f2bf((v.w - mu) * rs * gv.w + bv.w);
    ((ushort4*)(out + (size_t)row * E_DIM))[tid] = o;
}

// ---------------- LayerNorm (E=1024) + bf16 cast, bf16 input (x2 diet) -------------
__global__ __launch_bounds__(256)
void ln_kernel_bf(const u16* __restrict__ x, const float* __restrict__ g,
                  const float* __restrict__ b, u16* __restrict__ out) {
    int row = blockIdx.x;
    int tid = threadIdx.x;
    ushort4 uv = ((const ushort4*)(x + (size_t)row * E_DIM))[tid];
    float4 v;
    v.x = bf2f(uv.x); v.y = bf2f(uv.y); v.z = bf2f(uv.z); v.w = bf2f(uv.w);
    float s = v.x + v.y + v.z + v.w;
    float sq = v.x * v.x + v.y * v.y + v.z * v.z + v.w * v.w;
#pragma unroll
    for (int off = 32; off; off >>= 1) {
        s += __shfl_xor(s, off);
        sq += __shfl_xor(sq, off);
    }
    __shared__ float sh[8];
    int w = tid >> 6, lane = tid & 63;
    if (lane == 0) { sh[w] = s; sh[4 + w] = sq; }
    __syncthreads();
    s = sh[0] + sh[1] + sh[2] + sh[3];
    sq = sh[4] + sh[5] + sh[6] + sh[7];
    float mu = s * (1.f / E_DIM);
    float var = sq * (1.f / E_DIM) - mu * mu;
    float rs = rsqrtf(var + 1e-5f);
    float4 gv = ((const float4*)g)[tid];
    float4 bv = ((const float4*)b)[tid];
    ushort4 o;
    o.x = f2bf((v.x - mu) * rs * gv.x + bv.x);
    o.y = f2bf((v.y - mu) * rs * gv.y + bv.y);
    o.z = f2bf((v.z - mu) * rs * gv.z + bv.z);
    o.w = f2bf((v.w - mu) * rs * gv.w + bv.w);
    ((ushort4*)(out + (size_t)row * E_DIM))[tid] = o;
}

// ---------------- GEMM 256x128 tile, BK=64, 8 waves, 3-deep pipeline (R5) ----------
// MODE 0: bf16 out, QKV head-split; Q pre-scaled; V written DIRECTLY TRANSPOSED to
//         VT [B,H,64,T] via packed ushort4 (4 consecutive t per lane) -> outf=VT.
// MODE 1: bf16 out, +bias, ReLU
// MODE 2: bf16 out = f2bf(resid_f32 + acc + bias)   (x2 residual diet)
// MODE 4: f32 out = bf2f(resid_bf16) + acc + bias   (final W2)
template <int MODE>
__global__ __launch_bounds__(512)
void gemm_bt128(const u16* __restrict__ A, const u16* __restrict__ BT,
                int M, int N, int K,
                const float* __restrict__ bias, const void* __restrict__ residv,
                float* __restrict__ outf, u16* __restrict__ outb) {
    __shared__ __align__(16) u16 As[3][256 * 64];
    __shared__ __align__(16) u16 Bs[3][128 * 64];

    const int gx = gridDim.x;
    const int nwg = gx * gridDim.y;
    const int l = blockIdx.y * gx + blockIdx.x;
    const int sw = (l & 7) * (nwg >> 3) + (l >> 3);
    const int tRow = (sw / gx) * 256, tCol = (sw % gx) * 128;

    const int tid = threadIdx.x, w = tid >> 6, lane = tid & 63;
    const int wr = w >> 1, wc = w & 1, lr = lane & 15, hg = lane >> 4;
    const int nk = K >> 6;

    f32x4 z = {0.f, 0.f, 0.f, 0.f};
    f32x4 acc[4][4];
#pragma unroll
    for (int m = 0; m < 4; m++)
#pragma unroll
        for (int n = 0; n < 4; n++) acc[m][n] = z;

    auto STAGE_A = [&](int kt, int c) {
#pragma unroll
        for (int i = 0; i < 4; i++) {
            int chunk = i * 512 + tid;
            int row = chunk >> 3, j = chunk & 7;
            int js = (j ^ (row & 7)) << 3;
            async_copy16(A + (size_t)(tRow + row) * K + (kt << 6) + js,
                         &As[c][(i * 512 + w * 64) * 8]);
        }
    };
    auto STAGE_B = [&](int kt, int c) {
#pragma unroll
        for (int i = 0; i < 2; i++) {
            int chunk = i * 512 + tid;
            int row = chunk >> 3, j = chunk & 7;
            int js = (j ^ (row & 7)) << 3;
            async_copy16(BT + (size_t)(tCol + row) * K + (kt << 6) + js,
                         &Bs[c][(i * 512 + w * 64) * 8]);
        }
    };

    STAGE_A(0, 0); STAGE_B(0, 0);
    STAGE_A(1, 1); STAGE_B(1, 1);
    asm volatile("s_waitcnt vmcnt(6)" ::: "memory");
    asm volatile("s_barrier" ::: "memory");

    for (int t = 0; t < nk; ++t) {
        const int bu = t % 3, nx = (t + 2) % 3;
        const u16* Ab = &As[bu][0];
        const u16* Bb = &Bs[bu][0];
        const bool more = (t + 2 < nk);

        // ---- phase 0 ----
        s8v af0[2][2], bf[4][2];
#pragma unroll
        for (int m = 0; m < 2; m++)
#pragma unroll
            for (int kk = 0; kk < 2; kk++) {
                int r = wr * 64 + m * 16 + lr;
                af0[m][kk] = *(const s8v*)&Ab[r * 64 + (((kk * 4 + hg) ^ (r & 7)) << 3)];
            }
#pragma unroll
        for (int n = 0; n < 4; n++)
#pragma unroll
            for (int kk = 0; kk < 2; kk++) {
                int r = wc * 64 + n * 16 + lr;
                bf[n][kk] = *(const s8v*)&Bb[r * 64 + (((kk * 4 + hg) ^ (r & 7)) << 3)];
            }
        if (more) STAGE_A(t + 2, nx);
        asm volatile("s_barrier" ::: "memory");
        __builtin_amdgcn_s_setprio(1);
#pragma unroll
        for (int m = 0; m < 2; m++)
#pragma unroll
            for (int n = 0; n < 4; n++)
#pragma unroll
                for (int kk = 0; kk < 2; kk++)
                    acc[m][n] = __builtin_amdgcn_mfma_f32_16x16x32_bf16(
                        af0[m][kk], bf[n][kk], acc[m][n], 0, 0, 0);
        __builtin_amdgcn_s_setprio(0);
        asm volatile("s_barrier" ::: "memory");

        // ---- phase 1 ----
        s8v af1[2][2];
#pragma unroll
        for (int m = 0; m < 2; m++)
#pragma unroll
            for (int kk = 0; kk < 2; kk++) {
                int r = wr * 64 + (m + 2) * 16 + lr;
                af1[m][kk] = *(const s8v*)&Ab[r * 64 + (((kk * 4 + hg) ^ (r & 7)) << 3)];
            }
        if (more) STAGE_B(t + 2, nx);
        asm volatile("s_barrier" ::: "memory");
        __builtin_amdgcn_s_setprio(1);
#pragma unroll
        for (int m = 0; m < 2; m++)
#pragma unroll
            for (int n = 0; n < 4; n++)
#pragma unroll
                for (int kk = 0; kk < 2; kk++)
                    acc[m + 2][n] = __builtin_amdgcn_mfma_f32_16x16x32_bf16(
                        af1[m][kk], bf[n][kk], acc[m + 2][n], 0, 0, 0);
        __builtin_amdgcn_s_setprio(0);
        if (more) asm volatile("s_waitcnt vmcnt(6)" ::: "memory");
        else      asm volatile("s_waitcnt vmcnt(0)" ::: "memory");
        asm volatile("s_barrier" ::: "memory");
    }

#pragma unroll
    for (int m = 0; m < 4; m++)
#pragma unroll
        for (int n = 0; n < 4; n++) {
            if (MODE == 0) {
                int col = tCol + wc * 64 + n * 16 + lr;
                int type = col >> 10, c2 = col & 1023;
                int h = c2 >> 6, d = c2 & 63;
                int row0 = tRow + wr * 64 + m * 16 + hg * 4;
                int bb = row0 >> 11, t0 = row0 & 2047;
                if (type == 2) {
                    ushort4 pk;
                    pk.x = f2bf(acc[m][n][0]);
                    pk.y = f2bf(acc[m][n][1]);
                    pk.z = f2bf(acc[m][n][2]);
                    pk.w = f2bf(acc[m][n][3]);
                    u16* vt = (u16*)outf;
                    *(ushort4*)&vt[(((size_t)(bb * H_NUM + h) * 64 + d) << 11) + t0] = pk;
                } else {
#pragma unroll
                    for (int r = 0; r < 4; r++) {
                        float v = acc[m][n][r];
                        if (type == 0) v *= QSCALE;
                        outb[(size_t)type * 8388608 +
                             (((size_t)(bb * H_NUM + h) * T_SEQ + t0 + r) << 6) + d] = f2bf(v);
                    }
                }
            } else {
#pragma unroll
                for (int r = 0; r < 4; r++) {
                    int row = tRow + wr * 64 + m * 16 + hg * 4 + r;
                    int col = tCol + wc * 64 + n * 16 + lr;
                    float v = acc[m][n][r];
                    if (MODE == 1) {
                        v += bias[col];
                        v = fmaxf(v, 0.f);
                        outb[(size_t)row * N + col] = f2bf(v);
                    } else if (MODE == 2) {
                        const float* resid = (const float*)residv;
                        outb[(size_t)row * N + col] =
                            f2bf(resid[(size_t)row * N + col] + v + bias[col]);
                    } else {  // MODE 4
                        const u16* resid = (const u16*)residv;
                        outf[(size_t)row * N + col] =
                            bf2f(resid[(size_t)row * N + col]) + v + bias[col];
                    }
                }
            }
        }
}

// ---------------- GEMM 256x256 tile, BK=64, 8 waves (2Mx4N), deep-slack (R9) -------
// MODE 1: bf16 +bias ReLU (W1 only).
template <int MODE>
__global__ __launch_bounds__(512)
void gemm_bt256(const u16* __restrict__ A, const u16* __restrict__ BT,
                int M, int N, int Kst, int klen,
                const float* __restrict__ bias, const float* __restrict__ resid,
                float* __restrict__ outf, u16* __restrict__ outb) {
    __shared__ __align__(16) u16 As[2][256 * 64];
    __shared__ __align__(16) u16 Bs[2][256 * 64];

    const int gx = gridDim.x;  // N/256
    const int nwg = gx * gridDim.y;
    const int l = blockIdx.y * gx + blockIdx.x;
    const int sw = (l & 7) * (nwg >> 3) + (l >> 3);
    const int tRow = (sw / gx) * 256, tCol = (sw % gx) * 256;
    const size_t koff = (size_t)blockIdx.z * klen;
    const u16* Az = A + koff;
    const u16* BTz = BT + koff;

    const int tid = threadIdx.x, w = tid >> 6, lane = tid & 63;
    const int wr = w >> 2, wc = w & 3, lr = lane & 15, hg = lane >> 4;
    const int nk = klen >> 6;

    f32x4 z = {0.f, 0.f, 0.f, 0.f};
    f32x4 acc[8][4];
#pragma unroll
    for (int m = 0; m < 8; m++)
#pragma unroll
        for (int n = 0; n < 4; n++) acc[m][n] = z;

    auto STAGE_A = [&](int kt, int c, int h) {
#pragma unroll
        for (int i = 0; i < 2; i++) {
            int chunk = h * 1024 + i * 512 + tid;
            int row = chunk >> 3, j = chunk & 7;
            int js = (j ^ (row & 7)) << 3;
            async_copy16(Az + (size_t)(tRow + row) * Kst + (kt << 6) + js,
                         &As[c][(h * 1024 + i * 512 + w * 64) * 8]);
        }
    };
    auto STAGE_B = [&](int kt, int c, int h) {
#pragma unroll
        for (int i = 0; i < 2; i++) {
            int chunk = h * 1024 + i * 512 + tid;
            int row = chunk >> 3, j = chunk & 7;
            int js = (j ^ (row & 7)) << 3;
            async_copy16(BTz + (size_t)(tCol + row) * Kst + (kt << 6) + js,
                         &Bs[c][(h * 1024 + i * 512 + w * 64) * 8]);
        }
    };

    STAGE_B(0, 0, 0); STAGE_B(0, 0, 1); STAGE_A(0, 0, 0); STAGE_A(0, 0, 1);
    STAGE_B(1, 1, 0); STAGE_B(1, 1, 1); STAGE_A(1, 1, 0); STAGE_A(1, 1, 1);
    asm volatile("s_waitcnt vmcnt(6)" ::: "memory");
    asm volatile("s_barrier" ::: "memory");

    for (int t = 0; t < nk; ++t) {
        const int cur = t & 1;
        const u16* Ab = &As[cur][0];
        const u16* Bb = &Bs[cur][0];
        const bool more = (t + 2 < nk);

        s8v bf[4][2];
#pragma unroll
        for (int p = 0; p < 4; p++) {
            s8v af[2][2];
#pragma unroll
            for (int mm = 0; mm < 2; mm++)
#pragma unroll
                for (int kk = 0; kk < 2; kk++) {
                    int r = (2 * p + mm) * 32 + wr * 16 + lr;
                    af[mm][kk] = *(const s8v*)&Ab[r * 64 + (((kk * 4 + hg) ^ (r & 7)) << 3)];
                }
            if (p == 0) {
#pragma unroll
                for (int n = 0; n < 4; n++)
#pragma unroll
                    for (int kk = 0; kk < 2; kk++) {
                        int r = n * 64 + wc * 16 + lr;
                        bf[n][kk] = *(const s8v*)&Bb[r * 64 + (((kk * 4 + hg) ^ (r & 7)) << 3)];
                    }
            }
            if (more) {
                if (p == 0) STAGE_B(t + 2, cur, 0);
                else if (p == 1) STAGE_B(t + 2, cur, 1);
                else if (p == 2) STAGE_A(t + 2, cur, 0);
                else STAGE_A(t + 2, cur, 1);
            }
            asm volatile("s_barrier" ::: "memory");
            __builtin_amdgcn_s_setprio(1);
#pragma unroll
            for (int mm = 0; mm < 2; mm++)
#pragma unroll
                for (int n = 0; n < 4; n++)
#pragma unroll
                    for (int kk = 0; kk < 2; kk++)
                        acc[2 * p + mm][n] = __builtin_amdgcn_mfma_f32_16x16x32_bf16(
                            af[mm][kk], bf[n][kk], acc[2 * p + mm][n], 0, 0, 0);
            __builtin_amdgcn_s_setprio(0);
            if (p == 3) {
                if (more) asm volatile("s_waitcnt vmcnt(6)" ::: "memory");
                else      asm volatile("s_waitcnt vmcnt(0)" ::: "memory");
            }
            asm volatile("s_barrier" ::: "memory");
        }
    }

#pragma unroll
    for (int m = 0; m < 8; m++)
#pragma unroll
        for (int n = 0; n < 4; n++)
#pragma unroll
            for (int r = 0; r < 4; r++) {
                int row = tRow + m * 32 + wr * 16 + hg * 4 + r;
                int col = tCol + n * 64 + wc * 16 + lr;
                float v = acc[m][n][r];
                v += bias[col];
                v = fmaxf(v, 0.f);
                outb[(size_t)row * N + col] = f2bf(v);
            }
}

// ---------------- causal flash attention, HS=64, 4 waves, 64-row q-tiles -----------
// NEW: 4-wave blocks (256 thr), q-tile 64 rows, pairs (i, 31-i) -> perfectly uniform
// 33 units/block; grid (64 bh, 16 pairs) = 1024 blocks = 4/CU (LDS 40 KB), exactly
// one full round. bh on x keeps same-bh blocks co-located per XCD (R15 win kept).
__global__ __launch_bounds__(256)
void attn_kernel(const u16* __restrict__ Q, const u16* __restrict__ K,
                 const u16* __restrict__ VT, u16* __restrict__ O) {
    __shared__ u16 Ks[2][64 * 64];
    __shared__ u16 Vs[2][64 * 64];
    __shared__ u16 Pl[4][16 * 64];
    const int bh = blockIdx.x;
    const int pr = blockIdx.y;        // pair index 0..15
    const u16* Qh = Q + (size_t)bh * T_SEQ * HS;
    const u16* Kh = K + (size_t)bh * T_SEQ * HS;
    const u16* VTh = VT + (size_t)bh * T_SEQ * HS;
    const int tid = threadIdx.x, w = tid >> 6, lane = tid & 63;
    const int lr = lane & 15, hg = lane >> 4;
    const int swz = (lr & 7) << 3;
    const int bb = bh >> 4, hh = bh & 15;
    const f32x4 z = {0.f, 0.f, 0.f, 0.f};

    for (int half = 0; half < 2; ++half) {
        const int qt = half ? (31 - pr) : pr;   // 64-row tiles 0..31
        const int qb = qt * 64;
        const int nt = qt + 1;

        s8v qf[2];
        {
            const int qrow = qb + w * 16 + lr;
            qf[0] = *(const s8v*)(Qh + (size_t)qrow * HS + hg * 8);
            qf[1] = *(const s8v*)(Qh + (size_t)qrow * HS + 32 + hg * 8);
        }
        f32x4 o[4] = {z, z, z, z};
        float m_run[4] = {0.f, 0.f, 0.f, 0.f};
        float l_part[4] = {0.f, 0.f, 0.f, 0.f};

        // 256 threads stage 512 K-chunks + 512 V-chunks: 2 passes of 64/wave each
        auto STAGE = [&](int t, int c) {
#pragma unroll
            for (int i = 0; i < 2; i++) {
                int chunk = i * 256 + w * 64 + lane;
                int row = chunk >> 3, j = chunk & 7;
                int js = (j ^ (row & 7)) << 3;
                async_copy16(Kh + (size_t)t * (64 * HS) + row * HS + js,
                             &Ks[c][(i * 256 + w * 64) * 8]);
                async_copy16(VTh + (size_t)row * T_SEQ + t * 64 + js,
                             &Vs[c][(i * 256 + w * 64) * 8]);
            }
        };

        int cur = 0;
        STAGE(0, 0);
        __syncthreads();

        for (int t = 0; t < nt; ++t) {
            if (t + 1 < nt) STAGE(t + 1, cur ^ 1);

            f32x4 s[4];
            __builtin_amdgcn_s_setprio(1);
#pragma unroll
            for (int n = 0; n < 4; n++) {
                f32x4 a = z;
#pragma unroll
                for (int kc = 0; kc < 2; kc++) {
                    s8v bfr = *(const s8v*)&Ks[cur][((n * 16 + lr) * 64 + kc * 32 + hg * 8) ^ swz];
                    a = __builtin_amdgcn_mfma_f32_16x16x32_bf16(qf[kc], bfr, a, 0, 0, 0);
                }
                s[n] = a;
            }
            __builtin_amdgcn_s_setprio(0);
            if (t == qt) {  // single diagonal tile at 64-row granularity
#pragma unroll
                for (int n = 0; n < 4; n++)
#pragma unroll
                    for (int r = 0; r < 4; r++)
                        if ((t * 64 + n * 16 + lr) > (qb + w * 16 + hg * 4 + r))
                            s[n][r] = -1e30f;
            }
            float d0[4][4], p4[4][4];
#pragma unroll
            for (int n = 0; n < 4; n++)
#pragma unroll
                for (int r = 0; r < 4; r++) {
                    d0[n][r] = s[n][r] - m_run[r];
                    p4[n][r] = __builtin_amdgcn_exp2f(d0[n][r]);
                }
            float sm[4];
#pragma unroll
            for (int r = 0; r < 4; r++)
                sm[r] = (p4[0][r] + p4[1][r]) + (p4[2][r] + p4[3][r]);
            float smax = fmaxf(fmaxf(sm[0], sm[1]), fmaxf(sm[2], sm[3]));
            if (__any(!(smax <= 2048.f))) {
                float pm[4];
#pragma unroll
                for (int r = 0; r < 4; r++) {
                    float m0 = fmaxf(fmaxf(d0[0][r], d0[1][r]), fmaxf(d0[2][r], d0[3][r]));
                    m0 = fmaxf(m0, __shfl_xor(m0, 1));
                    m0 = fmaxf(m0, __shfl_xor(m0, 2));
                    m0 = fmaxf(m0, __shfl_xor(m0, 4));
                    m0 = fmaxf(m0, __shfl_xor(m0, 8));
                    pm[r] = fmaxf(m0, 0.f);
                }
#pragma unroll
                for (int r = 0; r < 4; r++) {
                    float al = __builtin_amdgcn_exp2f(-pm[r]);
                    m_run[r] += pm[r];
                    l_part[r] *= al;
                    o[0][r] *= al; o[1][r] *= al; o[2][r] *= al; o[3][r] *= al;
                }
#pragma unroll
                for (int n = 0; n < 4; n++)
#pragma unroll
                    for (int r = 0; r < 4; r++)
                        p4[n][r] = __builtin_amdgcn_exp2f(d0[n][r] - pm[r]);
#pragma unroll
                for (int r = 0; r < 4; r++)
                    sm[r] = (p4[0][r] + p4[1][r]) + (p4[2][r] + p4[3][r]);
            }
#pragma unroll
            for (int r = 0; r < 4; r++) l_part[r] += sm[r];
            u16* Pw = &Pl[w][0];
#pragma unroll
            for (int n = 0; n < 4; n++)
#pragma unroll
                for (int r = 0; r < 4; r++) {
                    int prow = hg * 4 + r;
                    Pw[(prow * 64 + n * 16 + lr) ^ ((prow & 7) << 3)] =
                        (u16)(__builtin_bit_cast(unsigned int, p4[n][r]) >> 16);
                }
            asm volatile("s_waitcnt lgkmcnt(0)" ::: "memory");
            __builtin_amdgcn_s_setprio(1);
#pragma unroll
            for (int n = 0; n < 4; n++) {
#pragma unroll
                for (int kc = 0; kc < 2; kc++) {
                    s8v pa = *(const s8v*)&Pw[(lr * 64 + kc * 32 + hg * 8) ^ swz];
                    s8v vb = *(const s8v*)&Vs[cur][((n * 16 + lr) * 64 + kc * 32 + hg * 8) ^ swz];
                    o[n] = __builtin_amdgcn_mfma_f32_16x16x32_bf16(pa, vb, o[n], 0, 0, 0);
                }
            }
            __builtin_amdgcn_s_setprio(0);
            __syncthreads();
            cur ^= 1;
        }
        float rl[4];
#pragma unroll
        for (int r = 0; r < 4; r++) {
            float lsum = l_part[r];
            lsum += __shfl_xor(lsum, 1);
            lsum += __shfl_xor(lsum, 2);
            lsum += __shfl_xor(lsum, 4);
            lsum += __shfl_xor(lsum, 8);
            rl[r] = 1.f / lsum;
        }
#pragma unroll
        for (int n = 0; n < 4; n++)
#pragma unroll
            for (int r = 0; r < 4; r++) {
                int trow = qb + w * 16 + hg * 4 + r;
                O[((size_t)(bb * T_SEQ + trow)) * E_DIM + hh * HS + n * 16 + lr] =
                    f2bf(o[n][r] * rl[r]);
            }
    }
}

// ---------------- launch ----------------
extern "C" void kernel_launch(void* const* d_in, const int* in_sizes, int n_in,
                              void* d_out, int out_size, void* d_ws, size_t ws_size,
                              hipStream_t stream) {
    (void)in_sizes; (void)n_in; (void)out_size; (void)ws_size;
    const float* x  = (const float*)d_in[0];
    const float* Wq = (const float*)d_in[1];
    const float* Wk = (const float*)d_in[2];
    const float* Wv = (const float*)d_in[3];
    const float* Wp = (const float*)d_in[4];
    const float* bp = (const float*)d_in[5];
    const float* W1 = (const float*)d_in[6];
    const float* b1 = (const float*)d_in[7];
    const float* W2 = (const float*)d_in[8];
    const float* b2 = (const float*)d_in[9];
    const float* g1  = (const float*)d_in[10];
    const float* be1 = (const float*)d_in[11];
    const float* g2  = (const float*)d_in[12];
    const float* be2 = (const float*)d_in[13];

    char* ws = (char*)d_ws;
    u16* wqkv_t  = (u16*)(ws);                          // [3072][1024] bf16, 6 MB
    u16* wp_t    = (u16*)(ws + 6291456);                // [1024][1024], 2 MB
    u16* w1_t    = (u16*)(ws + 8388608);                // [4096][1024], 8 MB
    u16* w2_t    = (u16*)(ws + 16777216);               // [1024][4096], 8 MB
    u16* h_bf    = (u16*)(ws + 25165824);               // [8192][1024], 16 MB (h1 / h2)
    u16* q_bf    = (u16*)(ws + 41943040);               // Q,K [B,H,T,64]; VT [B,H,64,T]; attn
    u16* vt_bf   = q_bf + 2 * 8388608;                  // VT written by QKV epilogue
    u16* attn_bf = q_bf + 3 * 8388608;
    u16* ff1     = q_bf;                                 // reuse 64 MB region (W1 out)
    u16* x2b     = (u16*)(ws + 109051904);              // [8192][1024] bf16, 16 MB

    dim3 b32(32, 8);
    transpose_cast4<<<dim3(32, 32, 4), b32, 0, stream>>>(Wq, Wk, Wv, Wp, wqkv_t, wp_t);
    transpose_cast_w12<<<dim3(128, 32, 2), b32, 0, stream>>>(W1, W2, w1_t, w2_t);

    ln_kernel<<<M_ROWS, 256, 0, stream>>>(x, g1, be1, h_bf);
    gemm_bt128<0><<<dim3(24, 32), 512, 0, stream>>>(h_bf, wqkv_t, M_ROWS, 3072, 1024,
                                                    nullptr, nullptr, (float*)vt_bf, q_bf);
    // attn: 4-wave blocks, 64-row q-tiles, (bh, pair) = (64, 16) = 1024 blocks
    attn_kernel<<<dim3(64, 16), 256, 0, stream>>>(q_bf, q_bf + 8388608, vt_bf, attn_bf);
    gemm_bt128<2><<<dim3(8, 32), 512, 0, stream>>>(attn_bf, wp_t, M_ROWS, 1024, 1024,
                                                   bp, x, nullptr, x2b);
    ln_kernel_bf<<<M_ROWS, 256, 0, stream>>>(x2b, g2, be2, h_bf);
    gemm_bt256<1><<<dim3(16, 32), 512, 0, stream>>>(h_bf, w1_t, M_ROWS, 4096, 1024, 1024,
                                                    b1, nullptr, nullptr, ff1);
    gemm_bt128<4><<<dim3(8, 32), 512, 0, stream>>>(ff1, w2_t, M_ROWS, 1024, 4096,
                                                   b2, x2b, (float*)d_out, nullptr);
}

// Round 18
// 334.807 us; speedup vs baseline: 1.1111x; 1.1111x over previous
//
#include <hip/hip_runtime.h>
#include <stdint.h>

typedef unsigned short u16;
typedef short s8v __attribute__((ext_vector_type(8)));
typedef float f32x4 __attribute__((ext_vector_type(4)));

#define B_SZ 4
#define T_SEQ 2048
#define E_DIM 1024
#define H_NUM 16
#define HS 64
#define FF_DIM 4096
#define M_ROWS 8192  // B*T
// Q pre-scale: E^-0.5 * log2(e) -> QK^T scores arrive in log2 domain
#define QSCALE 0.0450842200f

__device__ __forceinline__ u16 f2bf(float f) {
    unsigned int u = __builtin_bit_cast(unsigned int, f);
    u += 0x7fffu + ((u >> 16) & 1u);
    return (u16)(u >> 16);
}

__device__ __forceinline__ float bf2f(u16 u) {
    unsigned int v = ((unsigned int)u) << 16;
    return __builtin_bit_cast(float, v);
}

__device__ __forceinline__ void async_copy16(const void* g, void* l) {
    __builtin_amdgcn_global_load_lds(
        (const __attribute__((address_space(1))) unsigned int*)g,
        (__attribute__((address_space(3))) unsigned int*)l, 16, 0, 0);
}

// ------- batched transpose + cast for the four 1024x1024 weights (Wq,Wk,Wv,Wp) -----
__global__ __launch_bounds__(256)
void transpose_cast4(const float* __restrict__ s0, const float* __restrict__ s1,
                     const float* __restrict__ s2, const float* __restrict__ s3,
                     u16* __restrict__ dqkv, u16* __restrict__ dp) {
    __shared__ float tile[32][33];
    const int zz = blockIdx.z;
    const float* src = (zz == 0) ? s0 : (zz == 1) ? s1 : (zz == 2) ? s2 : s3;
    u16* dst = (zz < 3) ? dqkv + (size_t)zz * 1048576 : dp;
    int n0 = blockIdx.x * 32, k0 = blockIdx.y * 32;
    int tx = threadIdx.x, ty = threadIdx.y;
#pragma unroll
    for (int i = 0; i < 4; i++)
        tile[ty + i * 8][tx] = src[(size_t)(k0 + ty + i * 8) * 1024 + n0 + tx];
    __syncthreads();
#pragma unroll
    for (int i = 0; i < 4; i++)
        dst[(size_t)(n0 + ty + i * 8) * 1024 + k0 + tx] = f2bf(tile[tx][ty + i * 8]);
}

// ------- merged transpose + cast for W1 [1024][4096] and W2 [4096][1024] -----------
__global__ __launch_bounds__(256)
void transpose_cast_w12(const float* __restrict__ W1, const float* __restrict__ W2,
                        u16* __restrict__ d1, u16* __restrict__ d2) {
    __shared__ float tile[32][33];
    const int zz = blockIdx.z;
    const float* src;
    u16* dst;
    int n0, k0, N, K;
    if (zz == 0) {  // W1: src [1024][4096] -> dst [4096][1024]
        src = W1; dst = d1; N = 4096; K = 1024;
        n0 = blockIdx.x * 32; k0 = blockIdx.y * 32;
    } else {        // W2: src [4096][1024] -> dst [1024][4096]
        src = W2; dst = d2; N = 1024; K = 4096;
        int idx = blockIdx.y * 128 + blockIdx.x;   // 0..4095
        n0 = (idx & 31) * 32; k0 = (idx >> 5) * 32;
    }
    int tx = threadIdx.x, ty = threadIdx.y;
#pragma unroll
    for (int i = 0; i < 4; i++)
        tile[ty + i * 8][tx] = src[(size_t)(k0 + ty + i * 8) * N + n0 + tx];
    __syncthreads();
#pragma unroll
    for (int i = 0; i < 4; i++)
        dst[(size_t)(n0 + ty + i * 8) * K + k0 + tx] = f2bf(tile[tx][ty + i * 8]);
}

// ---------------- LayerNorm (E=1024) + bf16 cast, f32 input ------------------------
__global__ __launch_bounds__(256)
void ln_kernel(const float* __restrict__ x, const float* __restrict__ g,
               const float* __restrict__ b, u16* __restrict__ out) {
    int row = blockIdx.x;
    int tid = threadIdx.x;
    float4 v = ((const float4*)(x + (size_t)row * E_DIM))[tid];
    float s = v.x + v.y + v.z + v.w;
    float sq = v.x * v.x + v.y * v.y + v.z * v.z + v.w * v.w;
#pragma unroll
    for (int off = 32; off; off >>= 1) {
        s += __shfl_xor(s, off);
        sq += __shfl_xor(sq, off);
    }
    __shared__ float sh[8];
    int w = tid >> 6, lane = tid & 63;
    if (lane == 0) { sh[w] = s; sh[4 + w] = sq; }
    __syncthreads();
    s = sh[0] + sh[1] + sh[2] + sh[3];
    sq = sh[4] + sh[5] + sh[6] + sh[7];
    float mu = s * (1.f / E_DIM);
    float var = sq * (1.f / E_DIM) - mu * mu;
    float rs = rsqrtf(var + 1e-5f);
    float4 gv = ((const float4*)g)[tid];
    float4 bv = ((const float4*)b)[tid];
    ushort4 o;
    o.x = f2bf((v.x - mu) * rs * gv.x + bv.x);
    o.y = f2bf((v.y - mu) * rs * gv.y + bv.y);
    o.z = f2bf((v.z - mu) * rs * gv.z + bv.z);
    o.w = f2bf((v.w - mu) * rs * gv.w + bv.w);
    ((ushort4*)(out + (size_t)row * E_DIM))[tid] = o;
}

// ---------------- LayerNorm (E=1024) + bf16 cast, bf16 input (x2 diet) -------------
__global__ __launch_bounds__(256)
void ln_kernel_bf(const u16* __restrict__ x, const float* __restrict__ g,
                  const float* __restrict__ b, u16* __restrict__ out) {
    int row = blockIdx.x;
    int tid = threadIdx.x;
    ushort4 uv = ((const ushort4*)(x + (size_t)row * E_DIM))[tid];
    float4 v;
    v.x = bf2f(uv.x); v.y = bf2f(uv.y); v.z = bf2f(uv.z); v.w = bf2f(uv.w);
    float s = v.x + v.y + v.z + v.w;
    float sq = v.x * v.x + v.y * v.y + v.z * v.z + v.w * v.w;
#pragma unroll
    for (int off = 32; off; off >>= 1) {
        s += __shfl_xor(s, off);
        sq += __shfl_xor(sq, off);
    }
    __shared__ float sh[8];
    int w = tid >> 6, lane = tid & 63;
    if (lane == 0) { sh[w] = s; sh[4 + w] = sq; }
    __syncthreads();
    s = sh[0] + sh[1] + sh[2] + sh[3];
    sq = sh[4] + sh[5] + sh[6] + sh[7];
    float mu = s * (1.f / E_DIM);
    float var = sq * (1.f / E_DIM) - mu * mu;
    float rs = rsqrtf(var + 1e-5f);
    float4 gv = ((const float4*)g)[tid];
    float4 bv = ((const float4*)b)[tid];
    ushort4 o;
    o.x = f2bf((v.x - mu) * rs * gv.x + bv.x);
    o.y = f2bf((v.y - mu) * rs * gv.y + bv.y);
    o.z = f2bf((v.z - mu) * rs * gv.z + bv.z);
    o.w = f2bf((v.w - mu) * rs * gv.w + bv.w);
    ((ushort4*)(out + (size_t)row * E_DIM))[tid] = o;
}

// ---------------- GEMM 256x128 tile, BK=64, 8 waves, 3-deep pipeline (R5) ----------
// MODE 0: bf16 out, QKV head-split; Q pre-scaled; V written DIRECTLY TRANSPOSED to
//         VT [B,H,64,T] via packed ushort4 (4 consecutive t per lane) -> outf=VT.
// MODE 1: bf16 out, +bias, ReLU
// MODE 2: bf16 out = f2bf(resid_f32 + acc + bias)   (x2 residual diet)
// MODE 4: f32 out = bf2f(resid_bf16) + acc + bias   (final W2)
template <int MODE>
__global__ __launch_bounds__(512)
void gemm_bt128(const u16* __restrict__ A, const u16* __restrict__ BT,
                int M, int N, int K,
                const float* __restrict__ bias, const void* __restrict__ residv,
                float* __restrict__ outf, u16* __restrict__ outb) {
    __shared__ __align__(16) u16 As[3][256 * 64];
    __shared__ __align__(16) u16 Bs[3][128 * 64];

    const int gx = gridDim.x;
    const int nwg = gx * gridDim.y;
    const int l = blockIdx.y * gx + blockIdx.x;
    const int sw = (l & 7) * (nwg >> 3) + (l >> 3);
    const int tRow = (sw / gx) * 256, tCol = (sw % gx) * 128;

    const int tid = threadIdx.x, w = tid >> 6, lane = tid & 63;
    const int wr = w >> 1, wc = w & 1, lr = lane & 15, hg = lane >> 4;
    const int nk = K >> 6;

    f32x4 z = {0.f, 0.f, 0.f, 0.f};
    f32x4 acc[4][4];
#pragma unroll
    for (int m = 0; m < 4; m++)
#pragma unroll
        for (int n = 0; n < 4; n++) acc[m][n] = z;

    auto STAGE_A = [&](int kt, int c) {
#pragma unroll
        for (int i = 0; i < 4; i++) {
            int chunk = i * 512 + tid;
            int row = chunk >> 3, j = chunk & 7;
            int js = (j ^ (row & 7)) << 3;
            async_copy16(A + (size_t)(tRow + row) * K + (kt << 6) + js,
                         &As[c][(i * 512 + w * 64) * 8]);
        }
    };
    auto STAGE_B = [&](int kt, int c) {
#pragma unroll
        for (int i = 0; i < 2; i++) {
            int chunk = i * 512 + tid;
            int row = chunk >> 3, j = chunk & 7;
            int js = (j ^ (row & 7)) << 3;
            async_copy16(BT + (size_t)(tCol + row) * K + (kt << 6) + js,
                         &Bs[c][(i * 512 + w * 64) * 8]);
        }
    };

    STAGE_A(0, 0); STAGE_B(0, 0);
    STAGE_A(1, 1); STAGE_B(1, 1);
    asm volatile("s_waitcnt vmcnt(6)" ::: "memory");
    asm volatile("s_barrier" ::: "memory");

    for (int t = 0; t < nk; ++t) {
        const int bu = t % 3, nx = (t + 2) % 3;
        const u16* Ab = &As[bu][0];
        const u16* Bb = &Bs[bu][0];
        const bool more = (t + 2 < nk);

        // ---- phase 0 ----
        s8v af0[2][2], bf[4][2];
#pragma unroll
        for (int m = 0; m < 2; m++)
#pragma unroll
            for (int kk = 0; kk < 2; kk++) {
                int r = wr * 64 + m * 16 + lr;
                af0[m][kk] = *(const s8v*)&Ab[r * 64 + (((kk * 4 + hg) ^ (r & 7)) << 3)];
            }
#pragma unroll
        for (int n = 0; n < 4; n++)
#pragma unroll
            for (int kk = 0; kk < 2; kk++) {
                int r = wc * 64 + n * 16 + lr;
                bf[n][kk] = *(const s8v*)&Bb[r * 64 + (((kk * 4 + hg) ^ (r & 7)) << 3)];
            }
        if (more) STAGE_A(t + 2, nx);
        asm volatile("s_barrier" ::: "memory");
        __builtin_amdgcn_s_setprio(1);
#pragma unroll
        for (int m = 0; m < 2; m++)
#pragma unroll
            for (int n = 0; n < 4; n++)
#pragma unroll
                for (int kk = 0; kk < 2; kk++)
                    acc[m][n] = __builtin_amdgcn_mfma_f32_16x16x32_bf16(
                        af0[m][kk], bf[n][kk], acc[m][n], 0, 0, 0);
        __builtin_amdgcn_s_setprio(0);
        asm volatile("s_barrier" ::: "memory");

        // ---- phase 1 ----
        s8v af1[2][2];
#pragma unroll
        for (int m = 0; m < 2; m++)
#pragma unroll
            for (int kk = 0; kk < 2; kk++) {
                int r = wr * 64 + (m + 2) * 16 + lr;
                af1[m][kk] = *(const s8v*)&Ab[r * 64 + (((kk * 4 + hg) ^ (r & 7)) << 3)];
            }
        if (more) STAGE_B(t + 2, nx);
        asm volatile("s_barrier" ::: "memory");
        __builtin_amdgcn_s_setprio(1);
#pragma unroll
        for (int m = 0; m < 2; m++)
#pragma unroll
            for (int n = 0; n < 4; n++)
#pragma unroll
                for (int kk = 0; kk < 2; kk++)
                    acc[m + 2][n] = __builtin_amdgcn_mfma_f32_16x16x32_bf16(
                        af1[m][kk], bf[n][kk], acc[m + 2][n], 0, 0, 0);
        __builtin_amdgcn_s_setprio(0);
        if (more) asm volatile("s_waitcnt vmcnt(6)" ::: "memory");
        else      asm volatile("s_waitcnt vmcnt(0)" ::: "memory");
        asm volatile("s_barrier" ::: "memory");
    }

#pragma unroll
    for (int m = 0; m < 4; m++)
#pragma unroll
        for (int n = 0; n < 4; n++) {
            if (MODE == 0) {
                int col = tCol + wc * 64 + n * 16 + lr;
                int type = col >> 10, c2 = col & 1023;
                int h = c2 >> 6, d = c2 & 63;
                int row0 = tRow + wr * 64 + m * 16 + hg * 4;
                int bb = row0 >> 11, t0 = row0 & 2047;
                if (type == 2) {
                    ushort4 pk;
                    pk.x = f2bf(acc[m][n][0]);
                    pk.y = f2bf(acc[m][n][1]);
                    pk.z = f2bf(acc[m][n][2]);
                    pk.w = f2bf(acc[m][n][3]);
                    u16* vt = (u16*)outf;
                    *(ushort4*)&vt[(((size_t)(bb * H_NUM + h) * 64 + d) << 11) + t0] = pk;
                } else {
#pragma unroll
                    for (int r = 0; r < 4; r++) {
                        float v = acc[m][n][r];
                        if (type == 0) v *= QSCALE;
                        outb[(size_t)type * 8388608 +
                             (((size_t)(bb * H_NUM + h) * T_SEQ + t0 + r) << 6) + d] = f2bf(v);
                    }
                }
            } else {
#pragma unroll
                for (int r = 0; r < 4; r++) {
                    int row = tRow + wr * 64 + m * 16 + hg * 4 + r;
                    int col = tCol + wc * 64 + n * 16 + lr;
                    float v = acc[m][n][r];
                    if (MODE == 1) {
                        v += bias[col];
                        v = fmaxf(v, 0.f);
                        outb[(size_t)row * N + col] = f2bf(v);
                    } else if (MODE == 2) {
                        const float* resid = (const float*)residv;
                        outb[(size_t)row * N + col] =
                            f2bf(resid[(size_t)row * N + col] + v + bias[col]);
                    } else {  // MODE 4
                        const u16* resid = (const u16*)residv;
                        outf[(size_t)row * N + col] =
                            bf2f(resid[(size_t)row * N + col]) + v + bias[col];
                    }
                }
            }
        }
}

// ---------------- GEMM 256x256 tile, BK=64, 8 waves (2Mx4N), deep-slack (R9) -------
// MODE 1: bf16 +bias ReLU (W1 only).
template <int MODE>
__global__ __launch_bounds__(512)
void gemm_bt256(const u16* __restrict__ A, const u16* __restrict__ BT,
                int M, int N, int Kst, int klen,
                const float* __restrict__ bias, const float* __restrict__ resid,
                float* __restrict__ outf, u16* __restrict__ outb) {
    __shared__ __align__(16) u16 As[2][256 * 64];
    __shared__ __align__(16) u16 Bs[2][256 * 64];

    const int gx = gridDim.x;  // N/256
    const int nwg = gx * gridDim.y;
    const int l = blockIdx.y * gx + blockIdx.x;
    const int sw = (l & 7) * (nwg >> 3) + (l >> 3);
    const int tRow = (sw / gx) * 256, tCol = (sw % gx) * 256;
    const size_t koff = (size_t)blockIdx.z * klen;
    const u16* Az = A + koff;
    const u16* BTz = BT + koff;

    const int tid = threadIdx.x, w = tid >> 6, lane = tid & 63;
    const int wr = w >> 2, wc = w & 3, lr = lane & 15, hg = lane >> 4;
    const int nk = klen >> 6;

    f32x4 z = {0.f, 0.f, 0.f, 0.f};
    f32x4 acc[8][4];
#pragma unroll
    for (int m = 0; m < 8; m++)
#pragma unroll
        for (int n = 0; n < 4; n++) acc[m][n] = z;

    auto STAGE_A = [&](int kt, int c, int h) {
#pragma unroll
        for (int i = 0; i < 2; i++) {
            int chunk = h * 1024 + i * 512 + tid;
            int row = chunk >> 3, j = chunk & 7;
            int js = (j ^ (row & 7)) << 3;
            async_copy16(Az + (size_t)(tRow + row) * Kst + (kt << 6) + js,
                         &As[c][(h * 1024 + i * 512 + w * 64) * 8]);
        }
    };
    auto STAGE_B = [&](int kt, int c, int h) {
#pragma unroll
        for (int i = 0; i < 2; i++) {
            int chunk = h * 1024 + i * 512 + tid;
            int row = chunk >> 3, j = chunk & 7;
            int js = (j ^ (row & 7)) << 3;
            async_copy16(BTz + (size_t)(tCol + row) * Kst + (kt << 6) + js,
                         &Bs[c][(h * 1024 + i * 512 + w * 64) * 8]);
        }
    };

    STAGE_B(0, 0, 0); STAGE_B(0, 0, 1); STAGE_A(0, 0, 0); STAGE_A(0, 0, 1);
    STAGE_B(1, 1, 0); STAGE_B(1, 1, 1); STAGE_A(1, 1, 0); STAGE_A(1, 1, 1);
    asm volatile("s_waitcnt vmcnt(6)" ::: "memory");
    asm volatile("s_barrier" ::: "memory");

    for (int t = 0; t < nk; ++t) {
        const int cur = t & 1;
        const u16* Ab = &As[cur][0];
        const u16* Bb = &Bs[cur][0];
        const bool more = (t + 2 < nk);

        s8v bf[4][2];
#pragma unroll
        for (int p = 0; p < 4; p++) {
            s8v af[2][2];
#pragma unroll
            for (int mm = 0; mm < 2; mm++)
#pragma unroll
                for (int kk = 0; kk < 2; kk++) {
                    int r = (2 * p + mm) * 32 + wr * 16 + lr;
                    af[mm][kk] = *(const s8v*)&Ab[r * 64 + (((kk * 4 + hg) ^ (r & 7)) << 3)];
                }
            if (p == 0) {
#pragma unroll
                for (int n = 0; n < 4; n++)
#pragma unroll
                    for (int kk = 0; kk < 2; kk++) {
                        int r = n * 64 + wc * 16 + lr;
                        bf[n][kk] = *(const s8v*)&Bb[r * 64 + (((kk * 4 + hg) ^ (r & 7)) << 3)];
                    }
            }
            if (more) {
                if (p == 0) STAGE_B(t + 2, cur, 0);
                else if (p == 1) STAGE_B(t + 2, cur, 1);
                else if (p == 2) STAGE_A(t + 2, cur, 0);
                else STAGE_A(t + 2, cur, 1);
            }
            asm volatile("s_barrier" ::: "memory");
            __builtin_amdgcn_s_setprio(1);
#pragma unroll
            for (int mm = 0; mm < 2; mm++)
#pragma unroll
                for (int n = 0; n < 4; n++)
#pragma unroll
                    for (int kk = 0; kk < 2; kk++)
                        acc[2 * p + mm][n] = __builtin_amdgcn_mfma_f32_16x16x32_bf16(
                            af[mm][kk], bf[n][kk], acc[2 * p + mm][n], 0, 0, 0);
            __builtin_amdgcn_s_setprio(0);
            if (p == 3) {
                if (more) asm volatile("s_waitcnt vmcnt(6)" ::: "memory");
                else      asm volatile("s_waitcnt vmcnt(0)" ::: "memory");
            }
            asm volatile("s_barrier" ::: "memory");
        }
    }

#pragma unroll
    for (int m = 0; m < 8; m++)
#pragma unroll
        for (int n = 0; n < 4; n++)
#pragma unroll
            for (int r = 0; r < 4; r++) {
                int row = tRow + m * 32 + wr * 16 + hg * 4 + r;
                int col = tCol + n * 64 + wc * 16 + lr;
                float v = acc[m][n][r];
                v += bias[col];
                v = fmaxf(v, 0.f);
                outb[(size_t)row * N + col] = f2bf(v);
            }
}

// ---------------- causal flash attention, HS=64, 8 waves, paired q-tiles (R15) -----
// Grid (64 bh, 8 pair): same-bh blocks co-located per XCD (K/V L2 reuse).
// exp2-domain softmax (Q pre-scaled); sum-doubles-as-check; P->bf16 truncation.
__global__ __launch_bounds__(512)
void attn_kernel(const u16* __restrict__ Q, const u16* __restrict__ K,
                 const u16* __restrict__ VT, u16* __restrict__ O) {
    __shared__ u16 Ks[2][64 * 64];
    __shared__ u16 Vs[2][64 * 64];
    __shared__ u16 Pl[8][16 * 64];
    const int bh = blockIdx.x;
    const int pr = blockIdx.y;
    const u16* Qh = Q + (size_t)bh * T_SEQ * HS;
    const u16* Kh = K + (size_t)bh * T_SEQ * HS;
    const u16* VTh = VT + (size_t)bh * T_SEQ * HS;
    const int tid = threadIdx.x, w = tid >> 6, lane = tid & 63;
    const int lr = lane & 15, hg = lane >> 4;
    const int swz = (lr & 7) << 3;
    const int bb = bh >> 4, hh = bh & 15;
    const f32x4 z = {0.f, 0.f, 0.f, 0.f};

    for (int half = 0; half < 2; ++half) {
        const int qt = half ? (15 - pr) : pr;
        const int qb = qt * 128;
        const int nt = 2 * qt + 2;

        s8v qf[2];
        {
            const int qrow = qb + w * 16 + lr;
            qf[0] = *(const s8v*)(Qh + (size_t)qrow * HS + hg * 8);
            qf[1] = *(const s8v*)(Qh + (size_t)qrow * HS + 32 + hg * 8);
        }
        f32x4 o[4] = {z, z, z, z};
        float m_run[4] = {0.f, 0.f, 0.f, 0.f};
        float l_part[4] = {0.f, 0.f, 0.f, 0.f};

        auto STAGE = [&](int t, int c) {
            int chunk = tid;
            int row = chunk >> 3, j = chunk & 7;
            int js = (j ^ (row & 7)) << 3;
            async_copy16(Kh + (size_t)t * (64 * HS) + row * HS + js, &Ks[c][w * 512]);
            async_copy16(VTh + (size_t)row * T_SEQ + t * 64 + js, &Vs[c][w * 512]);
        };

        int cur = 0;
        STAGE(0, 0);
        __syncthreads();

        for (int t = 0; t < nt; ++t) {
            if (t + 1 < nt) STAGE(t + 1, cur ^ 1);

            f32x4 s[4];
            __builtin_amdgcn_s_setprio(1);
#pragma unroll
            for (int n = 0; n < 4; n++) {
                f32x4 a = z;
#pragma unroll
                for (int kc = 0; kc < 2; kc++) {
                    s8v bfr = *(const s8v*)&Ks[cur][((n * 16 + lr) * 64 + kc * 32 + hg * 8) ^ swz];
                    a = __builtin_amdgcn_mfma_f32_16x16x32_bf16(qf[kc], bfr, a, 0, 0, 0);
                }
                s[n] = a;
            }
            __builtin_amdgcn_s_setprio(0);
            const bool diag = (t >= nt - 2);
            if (diag) {
#pragma unroll
                for (int n = 0; n < 4; n++)
#pragma unroll
                    for (int r = 0; r < 4; r++)
                        if ((t * 64 + n * 16 + lr) > (qb + w * 16 + hg * 4 + r))
                            s[n][r] = -1e30f;
            }
            float d0[4][4], p4[4][4];
#pragma unroll
            for (int n = 0; n < 4; n++)
#pragma unroll
                for (int r = 0; r < 4; r++) {
                    d0[n][r] = s[n][r] - m_run[r];
                    p4[n][r] = __builtin_amdgcn_exp2f(d0[n][r]);
                }
            float sm[4];
#pragma unroll
            for (int r = 0; r < 4; r++)
                sm[r] = (p4[0][r] + p4[1][r]) + (p4[2][r] + p4[3][r]);
            float smax = fmaxf(fmaxf(sm[0], sm[1]), fmaxf(sm[2], sm[3]));
            if (__any(!(smax <= 2048.f))) {
                float pm[4];
#pragma unroll
                for (int r = 0; r < 4; r++) {
                    float m0 = fmaxf(fmaxf(d0[0][r], d0[1][r]), fmaxf(d0[2][r], d0[3][r]));
                    m0 = fmaxf(m0, __shfl_xor(m0, 1));
                    m0 = fmaxf(m0, __shfl_xor(m0, 2));
                    m0 = fmaxf(m0, __shfl_xor(m0, 4));
                    m0 = fmaxf(m0, __shfl_xor(m0, 8));
                    pm[r] = fmaxf(m0, 0.f);
                }
#pragma unroll
                for (int r = 0; r < 4; r++) {
                    float al = __builtin_amdgcn_exp2f(-pm[r]);
                    m_run[r] += pm[r];
                    l_part[r] *= al;
                    o[0][r] *= al; o[1][r] *= al; o[2][r] *= al; o[3][r] *= al;
                }
#pragma unroll
                for (int n = 0; n < 4; n++)
#pragma unroll
                    for (int r = 0; r < 4; r++)
                        p4[n][r] = __builtin_amdgcn_exp2f(d0[n][r] - pm[r]);
#pragma unroll
                for (int r = 0; r < 4; r++)
                    sm[r] = (p4[0][r] + p4[1][r]) + (p4[2][r] + p4[3][r]);
            }
#pragma unroll
            for (int r = 0; r < 4; r++) l_part[r] += sm[r];
            u16* Pw = &Pl[w][0];
#pragma unroll
            for (int n = 0; n < 4; n++)
#pragma unroll
                for (int r = 0; r < 4; r++) {
                    int prow = hg * 4 + r;
                    Pw[(prow * 64 + n * 16 + lr) ^ ((prow & 7) << 3)] =
                        (u16)(__builtin_bit_cast(unsigned int, p4[n][r]) >> 16);
                }
            asm volatile("s_waitcnt lgkmcnt(0)" ::: "memory");
            __builtin_amdgcn_s_setprio(1);
#pragma unroll
            for (int n = 0; n < 4; n++) {
#pragma unroll
                for (int kc = 0; kc < 2; kc++) {
                    s8v pa = *(const s8v*)&Pw[(lr * 64 + kc * 32 + hg * 8) ^ swz];
                    s8v vb = *(const s8v*)&Vs[cur][((n * 16 + lr) * 64 + kc * 32 + hg * 8) ^ swz];
                    o[n] = __builtin_amdgcn_mfma_f32_16x16x32_bf16(pa, vb, o[n], 0, 0, 0);
                }
            }
            __builtin_amdgcn_s_setprio(0);
            __syncthreads();
            cur ^= 1;
        }
        float rl[4];
#pragma unroll
        for (int r = 0; r < 4; r++) {
            float lsum = l_part[r];
            lsum += __shfl_xor(lsum, 1);
            lsum += __shfl_xor(lsum, 2);
            lsum += __shfl_xor(lsum, 4);
            lsum += __shfl_xor(lsum, 8);
            rl[r] = 1.f / lsum;
        }
#pragma unroll
        for (int n = 0; n < 4; n++)
#pragma unroll
            for (int r = 0; r < 4; r++) {
                int trow = qb + w * 16 + hg * 4 + r;
                O[((size_t)(bb * T_SEQ + trow)) * E_DIM + hh * HS + n * 16 + lr] =
                    f2bf(o[n][r] * rl[r]);
            }
    }
}

// ---------------- launch ----------------
extern "C" void kernel_launch(void* const* d_in, const int* in_sizes, int n_in,
                              void* d_out, int out_size, void* d_ws, size_t ws_size,
                              hipStream_t stream) {
    (void)in_sizes; (void)n_in; (void)out_size; (void)ws_size;
    const float* x  = (const float*)d_in[0];
    const float* Wq = (const float*)d_in[1];
    const float* Wk = (const float*)d_in[2];
    const float* Wv = (const float*)d_in[3];
    const float* Wp = (const float*)d_in[4];
    const float* bp = (const float*)d_in[5];
    const float* W1 = (const float*)d_in[6];
    const float* b1 = (const float*)d_in[7];
    const float* W2 = (const float*)d_in[8];
    const float* b2 = (const float*)d_in[9];
    const float* g1  = (const float*)d_in[10];
    const float* be1 = (const float*)d_in[11];
    const float* g2  = (const float*)d_in[12];
    const float* be2 = (const float*)d_in[13];

    char* ws = (char*)d_ws;
    u16* wqkv_t  = (u16*)(ws);                          // [3072][1024] bf16, 6 MB
    u16* wp_t    = (u16*)(ws + 6291456);                // [1024][1024], 2 MB
    u16* w1_t    = (u16*)(ws + 8388608);                // [4096][1024], 8 MB
    u16* w2_t    = (u16*)(ws + 16777216);               // [1024][4096], 8 MB
    u16* h_bf    = (u16*)(ws + 25165824);               // [8192][1024], 16 MB (h1 / h2)
    u16* q_bf    = (u16*)(ws + 41943040);               // Q,K [B,H,T,64]; VT [B,H,64,T]; attn
    u16* vt_bf   = q_bf + 2 * 8388608;                  // VT written by QKV epilogue
    u16* attn_bf = q_bf + 3 * 8388608;
    u16* ff1     = q_bf;                                 // reuse 64 MB region (W1 out)
    u16* x2b     = (u16*)(ws + 109051904);              // [8192][1024] bf16, 16 MB

    dim3 b32(32, 8);
    transpose_cast4<<<dim3(32, 32, 4), b32, 0, stream>>>(Wq, Wk, Wv, Wp, wqkv_t, wp_t);
    transpose_cast_w12<<<dim3(128, 32, 2), b32, 0, stream>>>(W1, W2, w1_t, w2_t);

    ln_kernel<<<M_ROWS, 256, 0, stream>>>(x, g1, be1, h_bf);
    gemm_bt128<0><<<dim3(24, 32), 512, 0, stream>>>(h_bf, wqkv_t, M_ROWS, 3072, 1024,
                                                    nullptr, nullptr, (float*)vt_bf, q_bf);
    attn_kernel<<<dim3(64, 8), 512, 0, stream>>>(q_bf, q_bf + 8388608, vt_bf, attn_bf);
    gemm_bt128<2><<<dim3(8, 32), 512, 0, stream>>>(attn_bf, wp_t, M_ROWS, 1024, 1024,
                                                   bp, x, nullptr, x2b);
    ln_kernel_bf<<<M_ROWS, 256, 0, stream>>>(x2b, g2, be2, h_bf);
    gemm_bt256<1><<<dim3(16, 32), 512, 0, stream>>>(h_bf, w1_t, M_ROWS, 4096, 1024, 1024,
                                                    b1, nullptr, nullptr, ff1);
    gemm_bt128<4><<<dim3(8, 32), 512, 0, stream>>>(ff1, w2_t, M_ROWS, 1024, 4096,
                                                   b2, x2b, (float*)d_out, nullptr);
}

// Round 19
// 330.496 us; speedup vs baseline: 1.1256x; 1.0130x over previous
//
#include <hip/hip_runtime.h>
#include <stdint.h>

typedef unsigned short u16;
typedef short s8v __attribute__((ext_vector_type(8)));
typedef float f32x4 __attribute__((ext_vector_type(4)));

#define B_SZ 4
#define T_SEQ 2048
#define E_DIM 1024
#define H_NUM 16
#define HS 64
#define FF_DIM 4096
#define M_ROWS 8192  // B*T
// Q pre-scale: E^-0.5 * log2(e) -> QK^T scores arrive in log2 domain
#define QSCALE 0.0450842200f

__device__ __forceinline__ u16 f2bf(float f) {
    unsigned int u = __builtin_bit_cast(unsigned int, f);
    u += 0x7fffu + ((u >> 16) & 1u);
    return (u16)(u >> 16);
}

__device__ __forceinline__ float bf2f(u16 u) {
    unsigned int v = ((unsigned int)u) << 16;
    return __builtin_bit_cast(float, v);
}

__device__ __forceinline__ void async_copy16(const void* g, void* l) {
    __builtin_amdgcn_global_load_lds(
        (const __attribute__((address_space(1))) unsigned int*)g,
        (__attribute__((address_space(3))) unsigned int*)l, 16, 0, 0);
}

// ---------------- merged prologue: all weight transposes + LN1 ---------------------
// flat id: [0,4096) Wq/Wk/Wv/Wp 1024^2 transposes; [4096,8192) W1; [8192,12288) W2;
// [12288,20480) LayerNorm rows. Block (32,8) = 256 threads.
__global__ __launch_bounds__(256)
void prep_kernel(const float* __restrict__ s0, const float* __restrict__ s1,
                 const float* __restrict__ s2, const float* __restrict__ s3,
                 u16* __restrict__ dqkv, u16* __restrict__ dp,
                 const float* __restrict__ W1, const float* __restrict__ W2,
                 u16* __restrict__ d1, u16* __restrict__ d2,
                 const float* __restrict__ x, const float* __restrict__ g,
                 const float* __restrict__ b, u16* __restrict__ lnout) {
    const int id = blockIdx.x;
    if (id < 12288) {
        __shared__ float tile[32][33];
        int tx = threadIdx.x, ty = threadIdx.y;
        const float* src;
        u16* dst;
        int n0, k0, N, K;
        if (id < 4096) {
            int zz = id >> 10, idx = id & 1023;
            src = (zz == 0) ? s0 : (zz == 1) ? s1 : (zz == 2) ? s2 : s3;
            dst = (zz < 3) ? dqkv + (size_t)zz * 1048576 : dp;
            N = 1024; K = 1024;
            n0 = (idx & 31) << 5; k0 = (idx >> 5) << 5;
        } else if (id < 8192) {
            int idx = id - 4096;          // W1 [1024][4096] -> [4096][1024]
            src = W1; dst = d1; N = 4096; K = 1024;
            n0 = (idx & 127) << 5; k0 = (idx >> 7) << 5;
        } else {
            int idx = id - 8192;          // W2 [4096][1024] -> [1024][4096]
            src = W2; dst = d2; N = 1024; K = 4096;
            n0 = (idx & 31) << 5; k0 = (idx >> 5) << 5;
        }
#pragma unroll
        for (int i = 0; i < 4; i++)
            tile[ty + i * 8][tx] = src[(size_t)(k0 + ty + i * 8) * N + n0 + tx];
        __syncthreads();
#pragma unroll
        for (int i = 0; i < 4; i++)
            dst[(size_t)(n0 + ty + i * 8) * K + k0 + tx] = f2bf(tile[tx][ty + i * 8]);
    } else {
        // LayerNorm (E=1024), one row per block, f32 in -> bf16 out
        int row = id - 12288;
        int tid = threadIdx.y * 32 + threadIdx.x;
        float4 v = ((const float4*)(x + (size_t)row * E_DIM))[tid];
        float s = v.x + v.y + v.z + v.w;
        float sq = v.x * v.x + v.y * v.y + v.z * v.z + v.w * v.w;
#pragma unroll
        for (int off = 32; off; off >>= 1) {
            s += __shfl_xor(s, off);
            sq += __shfl_xor(sq, off);
        }
        __shared__ float sh[8];
        int w = tid >> 6, lane = tid & 63;
        if (lane == 0) { sh[w] = s; sh[4 + w] = sq; }
        __syncthreads();
        s = sh[0] + sh[1] + sh[2] + sh[3];
        sq = sh[4] + sh[5] + sh[6] + sh[7];
        float mu = s * (1.f / E_DIM);
        float var = sq * (1.f / E_DIM) - mu * mu;
        float rs = rsqrtf(var + 1e-5f);
        float4 gv = ((const float4*)g)[tid];
        float4 bv = ((const float4*)b)[tid];
        ushort4 o;
        o.x = f2bf((v.x - mu) * rs * gv.x + bv.x);
        o.y = f2bf((v.y - mu) * rs * gv.y + bv.y);
        o.z = f2bf((v.z - mu) * rs * gv.z + bv.z);
        o.w = f2bf((v.w - mu) * rs * gv.w + bv.w);
        ((ushort4*)(lnout + (size_t)row * E_DIM))[tid] = o;
    }
}

// ---------------- LayerNorm (E=1024) + bf16 cast, bf16 input (x2 diet) -------------
__global__ __launch_bounds__(256)
void ln_kernel_bf(const u16* __restrict__ x, const float* __restrict__ g,
                  const float* __restrict__ b, u16* __restrict__ out) {
    int row = blockIdx.x;
    int tid = threadIdx.x;
    ushort4 uv = ((const ushort4*)(x + (size_t)row * E_DIM))[tid];
    float4 v;
    v.x = bf2f(uv.x); v.y = bf2f(uv.y); v.z = bf2f(uv.z); v.w = bf2f(uv.w);
    float s = v.x + v.y + v.z + v.w;
    float sq = v.x * v.x + v.y * v.y + v.z * v.z + v.w * v.w;
#pragma unroll
    for (int off = 32; off; off >>= 1) {
        s += __shfl_xor(s, off);
        sq += __shfl_xor(sq, off);
    }
    __shared__ float sh[8];
    int w = tid >> 6, lane = tid & 63;
    if (lane == 0) { sh[w] = s; sh[4 + w] = sq; }
    __syncthreads();
    s = sh[0] + sh[1] + sh[2] + sh[3];
    sq = sh[4] + sh[5] + sh[6] + sh[7];
    float mu = s * (1.f / E_DIM);
    float var = sq * (1.f / E_DIM) - mu * mu;
    float rs = rsqrtf(var + 1e-5f);
    float4 gv = ((const float4*)g)[tid];
    float4 bv = ((const float4*)b)[tid];
    ushort4 o;
    o.x = f2bf((v.x - mu) * rs * gv.x + bv.x);
    o.y = f2bf((v.y - mu) * rs * gv.y + bv.y);
    o.z = f2bf((v.z - mu) * rs * gv.z + bv.z);
    o.w = f2bf((v.w - mu) * rs * gv.w + bv.w);
    ((ushort4*)(out + (size_t)row * E_DIM))[tid] = o;
}

// ---------------- GEMM 256x128 tile, BK=64, 8 waves, 3-deep pipeline (R5) ----------
// MODE 0: bf16 out, QKV head-split; Q pre-scaled; V written DIRECTLY TRANSPOSED to
//         VT [B,H,64,T] via packed ushort4 (4 consecutive t per lane) -> outf=VT.
// MODE 1: bf16 out, +bias, ReLU
// MODE 2: bf16 out = f2bf(resid_f32 + acc + bias)   (x2 residual diet)
// MODE 4: f32 out = bf2f(resid_bf16) + acc + bias   (final W2)
template <int MODE>
__global__ __launch_bounds__(512)
void gemm_bt128(const u16* __restrict__ A, const u16* __restrict__ BT,
                int M, int N, int K,
                const float* __restrict__ bias, const void* __restrict__ residv,
                float* __restrict__ outf, u16* __restrict__ outb) {
    __shared__ __align__(16) u16 As[3][256 * 64];
    __shared__ __align__(16) u16 Bs[3][128 * 64];

    const int gx = gridDim.x;
    const int nwg = gx * gridDim.y;
    const int l = blockIdx.y * gx + blockIdx.x;
    const int sw = (l & 7) * (nwg >> 3) + (l >> 3);
    const int tRow = (sw / gx) * 256, tCol = (sw % gx) * 128;

    const int tid = threadIdx.x, w = tid >> 6, lane = tid & 63;
    const int wr = w >> 1, wc = w & 1, lr = lane & 15, hg = lane >> 4;
    const int nk = K >> 6;

    f32x4 z = {0.f, 0.f, 0.f, 0.f};
    f32x4 acc[4][4];
#pragma unroll
    for (int m = 0; m < 4; m++)
#pragma unroll
        for (int n = 0; n < 4; n++) acc[m][n] = z;

    auto STAGE_A = [&](int kt, int c) {
#pragma unroll
        for (int i = 0; i < 4; i++) {
            int chunk = i * 512 + tid;
            int row = chunk >> 3, j = chunk & 7;
            int js = (j ^ (row & 7)) << 3;
            async_copy16(A + (size_t)(tRow + row) * K + (kt << 6) + js,
                         &As[c][(i * 512 + w * 64) * 8]);
        }
    };
    auto STAGE_B = [&](int kt, int c) {
#pragma unroll
        for (int i = 0; i < 2; i++) {
            int chunk = i * 512 + tid;
            int row = chunk >> 3, j = chunk & 7;
            int js = (j ^ (row & 7)) << 3;
            async_copy16(BT + (size_t)(tCol + row) * K + (kt << 6) + js,
                         &Bs[c][(i * 512 + w * 64) * 8]);
        }
    };

    STAGE_A(0, 0); STAGE_B(0, 0);
    STAGE_A(1, 1); STAGE_B(1, 1);
    asm volatile("s_waitcnt vmcnt(6)" ::: "memory");
    asm volatile("s_barrier" ::: "memory");

    for (int t = 0; t < nk; ++t) {
        const int bu = t % 3, nx = (t + 2) % 3;
        const u16* Ab = &As[bu][0];
        const u16* Bb = &Bs[bu][0];
        const bool more = (t + 2 < nk);

        // ---- phase 0 ----
        s8v af0[2][2], bf[4][2];
#pragma unroll
        for (int m = 0; m < 2; m++)
#pragma unroll
            for (int kk = 0; kk < 2; kk++) {
                int r = wr * 64 + m * 16 + lr;
                af0[m][kk] = *(const s8v*)&Ab[r * 64 + (((kk * 4 + hg) ^ (r & 7)) << 3)];
            }
#pragma unroll
        for (int n = 0; n < 4; n++)
#pragma unroll
            for (int kk = 0; kk < 2; kk++) {
                int r = wc * 64 + n * 16 + lr;
                bf[n][kk] = *(const s8v*)&Bb[r * 64 + (((kk * 4 + hg) ^ (r & 7)) << 3)];
            }
        if (more) STAGE_A(t + 2, nx);
        asm volatile("s_barrier" ::: "memory");
        __builtin_amdgcn_s_setprio(1);
#pragma unroll
        for (int m = 0; m < 2; m++)
#pragma unroll
            for (int n = 0; n < 4; n++)
#pragma unroll
                for (int kk = 0; kk < 2; kk++)
                    acc[m][n] = __builtin_amdgcn_mfma_f32_16x16x32_bf16(
                        af0[m][kk], bf[n][kk], acc[m][n], 0, 0, 0);
        __builtin_amdgcn_s_setprio(0);
        asm volatile("s_barrier" ::: "memory");

        // ---- phase 1 ----
        s8v af1[2][2];
#pragma unroll
        for (int m = 0; m < 2; m++)
#pragma unroll
            for (int kk = 0; kk < 2; kk++) {
                int r = wr * 64 + (m + 2) * 16 + lr;
                af1[m][kk] = *(const s8v*)&Ab[r * 64 + (((kk * 4 + hg) ^ (r & 7)) << 3)];
            }
        if (more) STAGE_B(t + 2, nx);
        asm volatile("s_barrier" ::: "memory");
        __builtin_amdgcn_s_setprio(1);
#pragma unroll
        for (int m = 0; m < 2; m++)
#pragma unroll
            for (int n = 0; n < 4; n++)
#pragma unroll
                for (int kk = 0; kk < 2; kk++)
                    acc[m + 2][n] = __builtin_amdgcn_mfma_f32_16x16x32_bf16(
                        af1[m][kk], bf[n][kk], acc[m + 2][n], 0, 0, 0);
        __builtin_amdgcn_s_setprio(0);
        if (more) asm volatile("s_waitcnt vmcnt(6)" ::: "memory");
        else      asm volatile("s_waitcnt vmcnt(0)" ::: "memory");
        asm volatile("s_barrier" ::: "memory");
    }

#pragma unroll
    for (int m = 0; m < 4; m++)
#pragma unroll
        for (int n = 0; n < 4; n++) {
            if (MODE == 0) {
                int col = tCol + wc * 64 + n * 16 + lr;
                int type = col >> 10, c2 = col & 1023;
                int h = c2 >> 6, d = c2 & 63;
                int row0 = tRow + wr * 64 + m * 16 + hg * 4;
                int bb = row0 >> 11, t0 = row0 & 2047;
                if (type == 2) {
                    ushort4 pk;
                    pk.x = f2bf(acc[m][n][0]);
                    pk.y = f2bf(acc[m][n][1]);
                    pk.z = f2bf(acc[m][n][2]);
                    pk.w = f2bf(acc[m][n][3]);
                    u16* vt = (u16*)outf;
                    *(ushort4*)&vt[(((size_t)(bb * H_NUM + h) * 64 + d) << 11) + t0] = pk;
                } else {
#pragma unroll
                    for (int r = 0; r < 4; r++) {
                        float v = acc[m][n][r];
                        if (type == 0) v *= QSCALE;
                        outb[(size_t)type * 8388608 +
                             (((size_t)(bb * H_NUM + h) * T_SEQ + t0 + r) << 6) + d] = f2bf(v);
                    }
                }
            } else {
#pragma unroll
                for (int r = 0; r < 4; r++) {
                    int row = tRow + wr * 64 + m * 16 + hg * 4 + r;
                    int col = tCol + wc * 64 + n * 16 + lr;
                    float v = acc[m][n][r];
                    if (MODE == 1) {
                        v += bias[col];
                        v = fmaxf(v, 0.f);
                        outb[(size_t)row * N + col] = f2bf(v);
                    } else if (MODE == 2) {
                        const float* resid = (const float*)residv;
                        outb[(size_t)row * N + col] =
                            f2bf(resid[(size_t)row * N + col] + v + bias[col]);
                    } else {  // MODE 4
                        const u16* resid = (const u16*)residv;
                        outf[(size_t)row * N + col] =
                            bf2f(resid[(size_t)row * N + col]) + v + bias[col];
                    }
                }
            }
        }
}

// ---------------- GEMM 256x256 tile, BK=64, 8 waves (2Mx4N), deep-slack (R9) -------
// MODE 1: bf16 +bias ReLU (W1 only).
template <int MODE>
__global__ __launch_bounds__(512)
void gemm_bt256(const u16* __restrict__ A, const u16* __restrict__ BT,
                int M, int N, int Kst, int klen,
                const float* __restrict__ bias, const float* __restrict__ resid,
                float* __restrict__ outf, u16* __restrict__ outb) {
    __shared__ __align__(16) u16 As[2][256 * 64];
    __shared__ __align__(16) u16 Bs[2][256 * 64];

    const int gx = gridDim.x;  // N/256
    const int nwg = gx * gridDim.y;
    const int l = blockIdx.y * gx + blockIdx.x;
    const int sw = (l & 7) * (nwg >> 3) + (l >> 3);
    const int tRow = (sw / gx) * 256, tCol = (sw % gx) * 256;
    const size_t koff = (size_t)blockIdx.z * klen;
    const u16* Az = A + koff;
    const u16* BTz = BT + koff;

    const int tid = threadIdx.x, w = tid >> 6, lane = tid & 63;
    const int wr = w >> 2, wc = w & 3, lr = lane & 15, hg = lane >> 4;
    const int nk = klen >> 6;

    f32x4 z = {0.f, 0.f, 0.f, 0.f};
    f32x4 acc[8][4];
#pragma unroll
    for (int m = 0; m < 8; m++)
#pragma unroll
        for (int n = 0; n < 4; n++) acc[m][n] = z;

    auto STAGE_A = [&](int kt, int c, int h) {
#pragma unroll
        for (int i = 0; i < 2; i++) {
            int chunk = h * 1024 + i * 512 + tid;
            int row = chunk >> 3, j = chunk & 7;
            int js = (j ^ (row & 7)) << 3;
            async_copy16(Az + (size_t)(tRow + row) * Kst + (kt << 6) + js,
                         &As[c][(h * 1024 + i * 512 + w * 64) * 8]);
        }
    };
    auto STAGE_B = [&](int kt, int c, int h) {
#pragma unroll
        for (int i = 0; i < 2; i++) {
            int chunk = h * 1024 + i * 512 + tid;
            int row = chunk >> 3, j = chunk & 7;
            int js = (j ^ (row & 7)) << 3;
            async_copy16(BTz + (size_t)(tCol + row) * Kst + (kt << 6) + js,
                         &Bs[c][(h * 1024 + i * 512 + w * 64) * 8]);
        }
    };

    STAGE_B(0, 0, 0); STAGE_B(0, 0, 1); STAGE_A(0, 0, 0); STAGE_A(0, 0, 1);
    STAGE_B(1, 1, 0); STAGE_B(1, 1, 1); STAGE_A(1, 1, 0); STAGE_A(1, 1, 1);
    asm volatile("s_waitcnt vmcnt(6)" ::: "memory");
    asm volatile("s_barrier" ::: "memory");

    for (int t = 0; t < nk; ++t) {
        const int cur = t & 1;
        const u16* Ab = &As[cur][0];
        const u16* Bb = &Bs[cur][0];
        const bool more = (t + 2 < nk);

        s8v bf[4][2];
#pragma unroll
        for (int p = 0; p < 4; p++) {
            s8v af[2][2];
#pragma unroll
            for (int mm = 0; mm < 2; mm++)
#pragma unroll
                for (int kk = 0; kk < 2; kk++) {
                    int r = (2 * p + mm) * 32 + wr * 16 + lr;
                    af[mm][kk] = *(const s8v*)&Ab[r * 64 + (((kk * 4 + hg) ^ (r & 7)) << 3)];
                }
            if (p == 0) {
#pragma unroll
                for (int n = 0; n < 4; n++)
#pragma unroll
                    for (int kk = 0; kk < 2; kk++) {
                        int r = n * 64 + wc * 16 + lr;
                        bf[n][kk] = *(const s8v*)&Bb[r * 64 + (((kk * 4 + hg) ^ (r & 7)) << 3)];
                    }
            }
            if (more) {
                if (p == 0) STAGE_B(t + 2, cur, 0);
                else if (p == 1) STAGE_B(t + 2, cur, 1);
                else if (p == 2) STAGE_A(t + 2, cur, 0);
                else STAGE_A(t + 2, cur, 1);
            }
            asm volatile("s_barrier" ::: "memory");
            __builtin_amdgcn_s_setprio(1);
#pragma unroll
            for (int mm = 0; mm < 2; mm++)
#pragma unroll
                for (int n = 0; n < 4; n++)
#pragma unroll
                    for (int kk = 0; kk < 2; kk++)
                        acc[2 * p + mm][n] = __builtin_amdgcn_mfma_f32_16x16x32_bf16(
                            af[mm][kk], bf[n][kk], acc[2 * p + mm][n], 0, 0, 0);
            __builtin_amdgcn_s_setprio(0);
            if (p == 3) {
                if (more) asm volatile("s_waitcnt vmcnt(6)" ::: "memory");
                else      asm volatile("s_waitcnt vmcnt(0)" ::: "memory");
            }
            asm volatile("s_barrier" ::: "memory");
        }
    }

#pragma unroll
    for (int m = 0; m < 8; m++)
#pragma unroll
        for (int n = 0; n < 4; n++)
#pragma unroll
            for (int r = 0; r < 4; r++) {
                int row = tRow + m * 32 + wr * 16 + hg * 4 + r;
                int col = tCol + n * 64 + wc * 16 + lr;
                float v = acc[m][n][r];
                v += bias[col];
                v = fmaxf(v, 0.f);
                outb[(size_t)row * N + col] = f2bf(v);
            }
}

// ---------------- causal flash attention, HS=64, 8 waves, paired q-tiles (R15) -----
// Grid (64 bh, 8 pair): same-bh blocks co-located per XCD (K/V L2 reuse).
// exp2-domain softmax (Q pre-scaled); sum-doubles-as-check; P->bf16 truncation.
__global__ __launch_bounds__(512)
void attn_kernel(const u16* __restrict__ Q, const u16* __restrict__ K,
                 const u16* __restrict__ VT, u16* __restrict__ O) {
    __shared__ u16 Ks[2][64 * 64];
    __shared__ u16 Vs[2][64 * 64];
    __shared__ u16 Pl[8][16 * 64];
    const int bh = blockIdx.x;
    const int pr = blockIdx.y;
    const u16* Qh = Q + (size_t)bh * T_SEQ * HS;
    const u16* Kh = K + (size_t)bh * T_SEQ * HS;
    const u16* VTh = VT + (size_t)bh * T_SEQ * HS;
    const int tid = threadIdx.x, w = tid >> 6, lane = tid & 63;
    const int lr = lane & 15, hg = lane >> 4;
    const int swz = (lr & 7) << 3;
    const int bb = bh >> 4, hh = bh & 15;
    const f32x4 z = {0.f, 0.f, 0.f, 0.f};

    for (int half = 0; half < 2; ++half) {
        const int qt = half ? (15 - pr) : pr;
        const int qb = qt * 128;
        const int nt = 2 * qt + 2;

        s8v qf[2];
        {
            const int qrow = qb + w * 16 + lr;
            qf[0] = *(const s8v*)(Qh + (size_t)qrow * HS + hg * 8);
            qf[1] = *(const s8v*)(Qh + (size_t)qrow * HS + 32 + hg * 8);
        }
        f32x4 o[4] = {z, z, z, z};
        float m_run[4] = {0.f, 0.f, 0.f, 0.f};
        float l_part[4] = {0.f, 0.f, 0.f, 0.f};

        auto STAGE = [&](int t, int c) {
            int chunk = tid;
            int row = chunk >> 3, j = chunk & 7;
            int js = (j ^ (row & 7)) << 3;
            async_copy16(Kh + (size_t)t * (64 * HS) + row * HS + js, &Ks[c][w * 512]);
            async_copy16(VTh + (size_t)row * T_SEQ + t * 64 + js, &Vs[c][w * 512]);
        };

        int cur = 0;
        STAGE(0, 0);
        __syncthreads();

        for (int t = 0; t < nt; ++t) {
            if (t + 1 < nt) STAGE(t + 1, cur ^ 1);

            f32x4 s[4];
            __builtin_amdgcn_s_setprio(1);
#pragma unroll
            for (int n = 0; n < 4; n++) {
                f32x4 a = z;
#pragma unroll
                for (int kc = 0; kc < 2; kc++) {
                    s8v bfr = *(const s8v*)&Ks[cur][((n * 16 + lr) * 64 + kc * 32 + hg * 8) ^ swz];
                    a = __builtin_amdgcn_mfma_f32_16x16x32_bf16(qf[kc], bfr, a, 0, 0, 0);
                }
                s[n] = a;
            }
            __builtin_amdgcn_s_setprio(0);
            const bool diag = (t >= nt - 2);
            if (diag) {
#pragma unroll
                for (int n = 0; n < 4; n++)
#pragma unroll
                    for (int r = 0; r < 4; r++)
                        if ((t * 64 + n * 16 + lr) > (qb + w * 16 + hg * 4 + r))
                            s[n][r] = -1e30f;
            }
            float d0[4][4], p4[4][4];
#pragma unroll
            for (int n = 0; n < 4; n++)
#pragma unroll
                for (int r = 0; r < 4; r++) {
                    d0[n][r] = s[n][r] - m_run[r];
                    p4[n][r] = __builtin_amdgcn_exp2f(d0[n][r]);
                }
            float sm[4];
#pragma unroll
            for (int r = 0; r < 4; r++)
                sm[r] = (p4[0][r] + p4[1][r]) + (p4[2][r] + p4[3][r]);
            float smax = fmaxf(fmaxf(sm[0], sm[1]), fmaxf(sm[2], sm[3]));
            if (__any(!(smax <= 2048.f))) {
                float pm[4];
#pragma unroll
                for (int r = 0; r < 4; r++) {
                    float m0 = fmaxf(fmaxf(d0[0][r], d0[1][r]), fmaxf(d0[2][r], d0[3][r]));
                    m0 = fmaxf(m0, __shfl_xor(m0, 1));
                    m0 = fmaxf(m0, __shfl_xor(m0, 2));
                    m0 = fmaxf(m0, __shfl_xor(m0, 4));
                    m0 = fmaxf(m0, __shfl_xor(m0, 8));
                    pm[r] = fmaxf(m0, 0.f);
                }
#pragma unroll
                for (int r = 0; r < 4; r++) {
                    float al = __builtin_amdgcn_exp2f(-pm[r]);
                    m_run[r] += pm[r];
                    l_part[r] *= al;
                    o[0][r] *= al; o[1][r] *= al; o[2][r] *= al; o[3][r] *= al;
                }
#pragma unroll
                for (int n = 0; n < 4; n++)
#pragma unroll
                    for (int r = 0; r < 4; r++)
                        p4[n][r] = __builtin_amdgcn_exp2f(d0[n][r] - pm[r]);
#pragma unroll
                for (int r = 0; r < 4; r++)
                    sm[r] = (p4[0][r] + p4[1][r]) + (p4[2][r] + p4[3][r]);
            }
#pragma unroll
            for (int r = 0; r < 4; r++) l_part[r] += sm[r];
            u16* Pw = &Pl[w][0];
#pragma unroll
            for (int n = 0; n < 4; n++)
#pragma unroll
                for (int r = 0; r < 4; r++) {
                    int prow = hg * 4 + r;
                    Pw[(prow * 64 + n * 16 + lr) ^ ((prow & 7) << 3)] =
                        (u16)(__builtin_bit_cast(unsigned int, p4[n][r]) >> 16);
                }
            asm volatile("s_waitcnt lgkmcnt(0)" ::: "memory");
            __builtin_amdgcn_s_setprio(1);
#pragma unroll
            for (int n = 0; n < 4; n++) {
#pragma unroll
                for (int kc = 0; kc < 2; kc++) {
                    s8v pa = *(const s8v*)&Pw[(lr * 64 + kc * 32 + hg * 8) ^ swz];
                    s8v vb = *(const s8v*)&Vs[cur][((n * 16 + lr) * 64 + kc * 32 + hg * 8) ^ swz];
                    o[n] = __builtin_amdgcn_mfma_f32_16x16x32_bf16(pa, vb, o[n], 0, 0, 0);
                }
            }
            __builtin_amdgcn_s_setprio(0);
            __syncthreads();
            cur ^= 1;
        }
        float rl[4];
#pragma unroll
        for (int r = 0; r < 4; r++) {
            float lsum = l_part[r];
            lsum += __shfl_xor(lsum, 1);
            lsum += __shfl_xor(lsum, 2);
            lsum += __shfl_xor(lsum, 4);
            lsum += __shfl_xor(lsum, 8);
            rl[r] = 1.f / lsum;
        }
#pragma unroll
        for (int n = 0; n < 4; n++)
#pragma unroll
            for (int r = 0; r < 4; r++) {
                int trow = qb + w * 16 + hg * 4 + r;
                O[((size_t)(bb * T_SEQ + trow)) * E_DIM + hh * HS + n * 16 + lr] =
                    f2bf(o[n][r] * rl[r]);
            }
    }
}

// ---------------- launch ----------------
extern "C" void kernel_launch(void* const* d_in, const int* in_sizes, int n_in,
                              void* d_out, int out_size, void* d_ws, size_t ws_size,
                              hipStream_t stream) {
    (void)in_sizes; (void)n_in; (void)out_size; (void)ws_size;
    const float* x  = (const float*)d_in[0];
    const float* Wq = (const float*)d_in[1];
    const float* Wk = (const float*)d_in[2];
    const float* Wv = (const float*)d_in[3];
    const float* Wp = (const float*)d_in[4];
    const float* bp = (const float*)d_in[5];
    const float* W1 = (const float*)d_in[6];
    const float* b1 = (const float*)d_in[7];
    const float* W2 = (const float*)d_in[8];
    const float* b2 = (const float*)d_in[9];
    const float* g1  = (const float*)d_in[10];
    const float* be1 = (const float*)d_in[11];
    const float* g2  = (const float*)d_in[12];
    const float* be2 = (const float*)d_in[13];

    char* ws = (char*)d_ws;
    u16* wqkv_t  = (u16*)(ws);                          // [3072][1024] bf16, 6 MB
    u16* wp_t    = (u16*)(ws + 6291456);                // [1024][1024], 2 MB
    u16* w1_t    = (u16*)(ws + 8388608);                // [4096][1024], 8 MB
    u16* w2_t    = (u16*)(ws + 16777216);               // [1024][4096], 8 MB
    u16* h_bf    = (u16*)(ws + 25165824);               // [8192][1024], 16 MB (h1 / h2)
    u16* q_bf    = (u16*)(ws + 41943040);               // Q,K [B,H,T,64]; VT [B,H,64,T]; attn
    u16* vt_bf   = q_bf + 2 * 8388608;                  // VT written by QKV epilogue
    u16* attn_bf = q_bf + 3 * 8388608;
    u16* ff1     = q_bf;                                 // reuse 64 MB region (W1 out)
    u16* x2b     = (u16*)(ws + 109051904);              // [8192][1024] bf16, 16 MB

    // merged prologue: all weight transposes + LN1 in ONE dispatch (20480 blocks)
    prep_kernel<<<20480, dim3(32, 8), 0, stream>>>(Wq, Wk, Wv, Wp, wqkv_t, wp_t,
                                                   W1, W2, w1_t, w2_t,
                                                   x, g1, be1, h_bf);
    gemm_bt128<0><<<dim3(24, 32), 512, 0, stream>>>(h_bf, wqkv_t, M_ROWS, 3072, 1024,
                                                    nullptr, nullptr, (float*)vt_bf, q_bf);
    attn_kernel<<<dim3(64, 8), 512, 0, stream>>>(q_bf, q_bf + 8388608, vt_bf, attn_bf);
    gemm_bt128<2><<<dim3(8, 32), 512, 0, stream>>>(attn_bf, wp_t, M_ROWS, 1024, 1024,
                                                   bp, x, nullptr, x2b);
    ln_kernel_bf<<<M_ROWS, 256, 0, stream>>>(x2b, g2, be2, h_bf);
    gemm_bt256<1><<<dim3(16, 32), 512, 0, stream>>>(h_bf, w1_t, M_ROWS, 4096, 1024, 1024,
                                                    b1, nullptr, nullptr, ff1);
    gemm_bt128<4><<<dim3(8, 32), 512, 0, stream>>>(ff1, w2_t, M_ROWS, 1024, 4096,
                                                   b2, x2b, (float*)d_out, nullptr);
}